// Round 2
// 903.576 us; speedup vs baseline: 1.2161x; 1.2161x over previous
//
#include <hip/hip_runtime.h>
#include <stdint.h>

#define M_DIM 8192
#define N_DIM 11008
#define K_DIM 4096

// ---- main i8 GEMM geometry: 256x256 tile, 8 waves, BK=128 i8 (128 B rows) ----
#define BM 256
#define BN 256
#define BK 128
#define KTILES (K_DIM / BK)   // 32

// ---- fallback bf16 geometry ----
#define FBM 128
#define FBN 128

typedef __attribute__((ext_vector_type(4))) int i32x4;
typedef __attribute__((ext_vector_type(8))) short bf16x8;
typedef __attribute__((ext_vector_type(4))) float f32x4;

__device__ __forceinline__ void async_cp16(const void* g, void* lds_uniform) {
  __builtin_amdgcn_global_load_lds(
      (__attribute__((address_space(1))) void*)(uintptr_t)g,
      (__attribute__((address_space(3))) void*)(uintptr_t)lds_uniform,
      16, 0, 0);
}

__device__ __forceinline__ unsigned short f2bf(float f) {
  unsigned int u = __float_as_uint(f);
  u += 0x7fffu + ((u >> 16) & 1u);
  return (unsigned short)(u >> 16);
}
__device__ __forceinline__ unsigned short i2bf(int v) {
  return (unsigned short)(__float_as_uint((float)v) >> 16);
}

__device__ __forceinline__ int pack4(int a, int b, int c, int d) {
  return (a & 0xFF) | ((b & 0xFF) << 8) | ((c & 0xFF) << 16) | ((d & 0xFF) << 24);
}

// one block per row: row absmax -> quantize to i8 with step = max/127
__global__ __launch_bounds__(256) void quant_x(const float* __restrict__ x,
                                               signed char* __restrict__ xq,
                                               float* __restrict__ row_step) {
  __shared__ float red[256];
  const unsigned int row = blockIdx.x, t = threadIdx.x;
  const float* xr = x + (size_t)row * K_DIM;
  float4 v[4];
#pragma unroll
  for (int j = 0; j < 4; ++j)
    v[j] = *(const float4*)(xr + j * 1024 + t * 4);

  float m = 0.f;
#pragma unroll
  for (int j = 0; j < 4; ++j) {
    m = fmaxf(m, fmaxf(fmaxf(fabsf(v[j].x), fabsf(v[j].y)),
                       fmaxf(fabsf(v[j].z), fabsf(v[j].w))));
  }
  red[t] = m;
  __syncthreads();
#pragma unroll
  for (int s = 128; s > 0; s >>= 1) {
    if (t < s) red[t] = fmaxf(red[t], red[t + s]);
    __syncthreads();
  }
  const float mx = red[0];
  const float r = (mx > 0.f) ? 127.0f / mx : 0.0f;
  if (t == 0) row_step[row] = (mx > 0.f) ? mx / 127.0f : 0.0f;

  int* out = (int*)(xq + (size_t)row * K_DIM);
#pragma unroll
  for (int j = 0; j < 4; ++j) {
    int q0 = __float2int_rn(v[j].x * r);
    int q1 = __float2int_rn(v[j].y * r);
    int q2 = __float2int_rn(v[j].z * r);
    int q3 = __float2int_rn(v[j].w * r);
    out[j * 256 + t] = pack4(q0, q1, q2, q3);
  }
}

// int32 weights {-1,0,1} -> i8 (exact)
__global__ __launch_bounds__(256) void quant_w(const int4* __restrict__ w,
                                               int* __restrict__ wq) {
  const size_t base = (size_t)blockIdx.x * 1024 + threadIdx.x;
#pragma unroll
  for (int j = 0; j < 4; ++j) {
    int4 a = w[base + j * 256];
    wq[base + j * 256] = pack4(a.x, a.y, a.z, a.w);
  }
}

// ---------------------------------------------------------------------------
// One K-tile (BK=128) of the 8-wave 256x256 i8 GEMM.
// 4 phases x {ds_read subtile | issue stage | barrier | lgkm0 | 16 MFMA | barrier}.
// Swizzle: chunk c (16B) of row r lives at LDS slot c ^ (r&7); global source is
// pre-swizzled so global_load_lds' linear dest lands data swizzled (rule #21).
// ---------------------------------------------------------------------------
__device__ __forceinline__ void ktile_iter(
    const signed char* Ab, const signed char* Bb,
    signed char* An, signed char* Bn, bool pf,
    i32x4 (&acc)[8][4],
    const signed char* (&ag)[4], const signed char* (&bg)[4],
    unsigned abase, unsigned bbase, unsigned ldsw)
{
  // B fragments for the whole K-tile stay in registers (8 x i32x4)
  i32x4 bfr[4][2];
#pragma unroll
  for (int ni = 0; ni < 4; ++ni)
#pragma unroll
    for (int ks = 0; ks < 2; ++ks)
      bfr[ni][ks] = *(const i32x4*)(Bb + ((bbase + ni * 2048u) ^ (unsigned)(ks << 6)));

  i32x4 afr[2][2];

  // ---------------- phase 0: mi 0-1 ----------------
#pragma unroll
  for (int mi = 0; mi < 2; ++mi)
#pragma unroll
    for (int ks = 0; ks < 2; ++ks)
      afr[mi][ks] = *(const i32x4*)(Ab + ((abase + mi * 2048u) ^ (unsigned)(ks << 6)));
  if (pf) {
    async_cp16(ag[0], An + 0 * 8192 + ldsw);
    async_cp16(ag[1], An + 1 * 8192 + ldsw);
    async_cp16(bg[0], Bn + 0 * 8192 + ldsw);
    async_cp16(bg[1], Bn + 1 * 8192 + ldsw);
  }
  __builtin_amdgcn_s_barrier();
  asm volatile("s_waitcnt lgkmcnt(0)" ::: "memory");
  __builtin_amdgcn_sched_barrier(0);
  __builtin_amdgcn_s_setprio(1);
#pragma unroll
  for (int mi = 0; mi < 2; ++mi)
#pragma unroll
    for (int ni = 0; ni < 4; ++ni)
#pragma unroll
      for (int ks = 0; ks < 2; ++ks)
        acc[mi][ni] = __builtin_amdgcn_mfma_i32_16x16x64_i8(afr[mi][ks], bfr[ni][ks], acc[mi][ni], 0, 0, 0);
  __builtin_amdgcn_s_setprio(0);
  __builtin_amdgcn_s_barrier();

  // ---------------- phase 1: mi 2-3 ----------------
#pragma unroll
  for (int mi = 0; mi < 2; ++mi)
#pragma unroll
    for (int ks = 0; ks < 2; ++ks)
      afr[mi][ks] = *(const i32x4*)(Ab + ((abase + (mi + 2) * 2048u) ^ (unsigned)(ks << 6)));
  if (pf) {
    async_cp16(ag[2], An + 2 * 8192 + ldsw);
    async_cp16(ag[3], An + 3 * 8192 + ldsw);
    async_cp16(bg[2], Bn + 2 * 8192 + ldsw);
    async_cp16(bg[3], Bn + 3 * 8192 + ldsw);
  }
  __builtin_amdgcn_s_barrier();
  asm volatile("s_waitcnt lgkmcnt(0)" ::: "memory");
  __builtin_amdgcn_sched_barrier(0);
  __builtin_amdgcn_s_setprio(1);
#pragma unroll
  for (int mi = 0; mi < 2; ++mi)
#pragma unroll
    for (int ni = 0; ni < 4; ++ni)
#pragma unroll
      for (int ks = 0; ks < 2; ++ks)
        acc[mi + 2][ni] = __builtin_amdgcn_mfma_i32_16x16x64_i8(afr[mi][ks], bfr[ni][ks], acc[mi + 2][ni], 0, 0, 0);
  __builtin_amdgcn_s_setprio(0);
  __builtin_amdgcn_s_barrier();

  // ---------------- phase 2: mi 4-5 ----------------
#pragma unroll
  for (int mi = 0; mi < 2; ++mi)
#pragma unroll
    for (int ks = 0; ks < 2; ++ks)
      afr[mi][ks] = *(const i32x4*)(Ab + ((abase + (mi + 4) * 2048u) ^ (unsigned)(ks << 6)));
  __builtin_amdgcn_s_barrier();
  asm volatile("s_waitcnt lgkmcnt(0)" ::: "memory");
  __builtin_amdgcn_sched_barrier(0);
  __builtin_amdgcn_s_setprio(1);
#pragma unroll
  for (int mi = 0; mi < 2; ++mi)
#pragma unroll
    for (int ni = 0; ni < 4; ++ni)
#pragma unroll
      for (int ks = 0; ks < 2; ++ks)
        acc[mi + 4][ni] = __builtin_amdgcn_mfma_i32_16x16x64_i8(afr[mi][ks], bfr[ni][ks], acc[mi + 4][ni], 0, 0, 0);
  __builtin_amdgcn_s_setprio(0);
  __builtin_amdgcn_s_barrier();

  // ---------------- phase 3: mi 6-7 (+ stage drain) ----------------
#pragma unroll
  for (int mi = 0; mi < 2; ++mi)
#pragma unroll
    for (int ks = 0; ks < 2; ++ks)
      afr[mi][ks] = *(const i32x4*)(Ab + ((abase + (mi + 6) * 2048u) ^ (unsigned)(ks << 6)));
  __builtin_amdgcn_s_barrier();
  asm volatile("s_waitcnt lgkmcnt(0)" ::: "memory");
  __builtin_amdgcn_sched_barrier(0);
  __builtin_amdgcn_s_setprio(1);
#pragma unroll
  for (int mi = 0; mi < 2; ++mi)
#pragma unroll
    for (int ni = 0; ni < 4; ++ni)
#pragma unroll
      for (int ks = 0; ks < 2; ++ks)
        acc[mi + 6][ni] = __builtin_amdgcn_mfma_i32_16x16x64_i8(afr[mi][ks], bfr[ni][ks], acc[mi + 6][ni], 0, 0, 0);
  __builtin_amdgcn_s_setprio(0);
  // stages for the next tile were issued >=2 phases ago (L2/L3 hits) -> cheap
  asm volatile("s_waitcnt vmcnt(0)" ::: "memory");
  __builtin_amdgcn_s_barrier();

#pragma unroll
  for (int g = 0; g < 4; ++g) { ag[g] += BK; bg[g] += BK; }
}

// ---- main GEMM: A (MxK i8), B (NxK i8), C = (A*B^T)_i32 * (row_step*w_scale) + bias ----
__global__ __launch_bounds__(512, 2) void gemm_i8(
    const signed char* __restrict__ A,
    const signed char* __restrict__ B,
    const float* __restrict__ row_step,
    const float* __restrict__ bias,
    const float* __restrict__ scale_p,
    float* __restrict__ C)
{
  __shared__ __align__(16) signed char As[2][BM * BK];   // 2 x 32 KB
  __shared__ __align__(16) signed char Bs[2][BN * BK];   // 2 x 32 KB (128 KiB total)

  const unsigned t = threadIdx.x;
  const unsigned lane = t & 63u;
  const unsigned wave = t >> 6;
  const unsigned n0 = blockIdx.x * BN;
  const unsigned m0 = blockIdx.y * BM;

  const unsigned wm = (wave >> 2) * 128u;   // 2 M wave-rows
  const unsigned wn = (wave & 3u) * 64u;    // 4 N wave-cols
  const unsigned fr = lane & 15u;
  const unsigned fq = lane >> 4;

  // staging: thread t covers row g*64 + (t>>3), 16B chunk cst (pre-swizzled
  // global source so linear global_load_lds dest realizes slot = c ^ (row&7))
  const unsigned rst = t >> 3;
  const unsigned cst = (lane & 7u) ^ ((lane >> 3) & 7u);
  const signed char* ag[4];
  const signed char* bg[4];
#pragma unroll
  for (int g = 0; g < 4; ++g) {
    ag[g] = A + (size_t)(m0 + g * 64 + rst) * K_DIM + cst * 16u;
    bg[g] = B + (size_t)(n0 + g * 64 + rst) * K_DIM + cst * 16u;
  }
  const unsigned ldsw = wave * 1024u;   // wave-uniform LDS base (HW adds lane*16)

  // fragment read offset: row*128 + ((ks*4+fq) ^ (fr&7))*16, expressed as
  // base + mi*2048, with ks toggled via XOR of bit 6
  const unsigned swz = ((fq ^ (fr & 3u)) << 4) | (((fr >> 2) & 1u) << 6);
  const unsigned abase = (wm + fr) * BK + swz;
  const unsigned bbase = (wn + fr) * BK + swz;

  i32x4 acc[8][4];
#pragma unroll
  for (int i = 0; i < 8; ++i)
#pragma unroll
    for (int j = 0; j < 4; ++j)
      acc[i][j] = (i32x4){0, 0, 0, 0};

  // prologue: stage K-tile 0 into buffer 0
#pragma unroll
  for (int g = 0; g < 4; ++g) {
    async_cp16(ag[g], As[0] + g * 8192 + ldsw);
    async_cp16(bg[g], Bs[0] + g * 8192 + ldsw);
    ag[g] += BK; bg[g] += BK;
  }
  asm volatile("s_waitcnt vmcnt(0)" ::: "memory");
  __builtin_amdgcn_s_barrier();

  for (int kt = 0; kt < KTILES; kt += 2) {
    ktile_iter(As[0], Bs[0], As[1], Bs[1], true,
               acc, ag, bg, abase, bbase, ldsw);
    ktile_iter(As[1], Bs[1], As[0], Bs[0], (kt + 2) < KTILES,
               acc, ag, bg, abase, bbase, ldsw);
  }

  // epilogue: dequant + bias, C layout: col = fr, row = fq*4 + r (verified)
  const float ws = scale_p[0];
  float bb[4];
#pragma unroll
  for (int ni = 0; ni < 4; ++ni)
    bb[ni] = bias[n0 + wn + ni * 16 + fr];

#pragma unroll
  for (int mi = 0; mi < 8; ++mi) {
    const unsigned mg = m0 + wm + mi * 16 + fq * 4;
    const float rs0 = row_step[mg + 0] * ws;
    const float rs1 = row_step[mg + 1] * ws;
    const float rs2 = row_step[mg + 2] * ws;
    const float rs3 = row_step[mg + 3] * ws;
#pragma unroll
    for (int ni = 0; ni < 4; ++ni) {
      const unsigned ng = n0 + wn + ni * 16 + fr;
      i32x4 v = acc[mi][ni];
      float* cp = C + (size_t)mg * N_DIM + ng;
      cp[0]                   = (float)v[0] * rs0 + bb[ni];
      cp[(size_t)1 * N_DIM]   = (float)v[1] * rs1 + bb[ni];
      cp[(size_t)2 * N_DIM]   = (float)v[2] * rs2 + bb[ni];
      cp[(size_t)3 * N_DIM]   = (float)v[3] * rs3 + bb[ni];
    }
  }
}

// ---- fallback (ws too small): bf16 fused convert-in-staging (correct, slower) ----
__global__ __launch_bounds__(256) void gemm_fused(
    const float* __restrict__ X,
    const int* __restrict__ W,
    const float* __restrict__ bias,
    const float* __restrict__ scale_p,
    float* __restrict__ C)
{
  __shared__ __align__(16) unsigned short As[FBM * 32];
  __shared__ __align__(16) unsigned short Bs[FBN * 32];

  const unsigned int t = threadIdx.x;
  const unsigned int n0 = blockIdx.x * FBN;
  const unsigned int m0 = blockIdx.y * FBM;
  const unsigned int lane = t & 63u;
  const unsigned int wave = t >> 6;
  const unsigned int wm = (wave >> 1) * 64u;
  const unsigned int wn = (wave & 1u) * 64u;
  const unsigned int fr = lane & 15u;
  const unsigned int fq = lane >> 4;

  const unsigned short* afp = As + (wm + fr) * 32 + fq * 8u;
  const unsigned short* bfp = Bs + (wn + fr) * 32 + fq * 8u;
  const unsigned int brow = t >> 1, bcol = (t & 1u) * 16u;

  f32x4 acc[4][4];
#pragma unroll
  for (int i = 0; i < 4; ++i)
#pragma unroll
    for (int j = 0; j < 4; ++j)
      acc[i][j] = (f32x4){0.f, 0.f, 0.f, 0.f};

  for (int kt = 0; kt < K_DIM; kt += 32) {
#pragma unroll
    for (int i = 0; i < 4; ++i) {
      unsigned int c = t + i * 256;
      unsigned int row = c >> 3, col = (c & 7u) * 4u;
      float4 v = *(const float4*)(X + (size_t)(m0 + row) * K_DIM + kt + col);
      ushort4 o;
      o.x = f2bf(v.x); o.y = f2bf(v.y); o.z = f2bf(v.z); o.w = f2bf(v.w);
      *(ushort4*)(As + row * 32 + col) = o;
    }
    {
      const int* wp = W + (size_t)(n0 + brow) * K_DIM + kt + bcol;
      int4 a = *(const int4*)(wp);
      int4 b = *(const int4*)(wp + 4);
      int4 c = *(const int4*)(wp + 8);
      int4 d = *(const int4*)(wp + 12);
      uint4 o0, o1;
      o0.x = (unsigned int)i2bf(a.x) | ((unsigned int)i2bf(a.y) << 16);
      o0.y = (unsigned int)i2bf(a.z) | ((unsigned int)i2bf(a.w) << 16);
      o0.z = (unsigned int)i2bf(b.x) | ((unsigned int)i2bf(b.y) << 16);
      o0.w = (unsigned int)i2bf(b.z) | ((unsigned int)i2bf(b.w) << 16);
      o1.x = (unsigned int)i2bf(c.x) | ((unsigned int)i2bf(c.y) << 16);
      o1.y = (unsigned int)i2bf(c.z) | ((unsigned int)i2bf(c.w) << 16);
      o1.z = (unsigned int)i2bf(d.x) | ((unsigned int)i2bf(d.y) << 16);
      o1.w = (unsigned int)i2bf(d.z) | ((unsigned int)i2bf(d.w) << 16);
      *(uint4*)(Bs + brow * 32 + bcol)     = o0;
      *(uint4*)(Bs + brow * 32 + bcol + 8) = o1;
    }
    __syncthreads();

    bf16x8 af[4], bgf[4];
#pragma unroll
    for (int mi = 0; mi < 4; ++mi)
      af[mi] = *(const bf16x8*)(afp + mi * 16 * 32);
#pragma unroll
    for (int ni = 0; ni < 4; ++ni)
      bgf[ni] = *(const bf16x8*)(bfp + ni * 16 * 32);
#pragma unroll
    for (int mi = 0; mi < 4; ++mi)
#pragma unroll
      for (int ni = 0; ni < 4; ++ni)
        acc[mi][ni] = __builtin_amdgcn_mfma_f32_16x16x32_bf16(af[mi], bgf[ni], acc[mi][ni], 0, 0, 0);
    __syncthreads();
  }

  const float scale = scale_p[0];
#pragma unroll
  for (int ni = 0; ni < 4; ++ni) {
    const unsigned int ng = n0 + wn + ni * 16 + fr;
    const float bbv = bias[ng];
#pragma unroll
    for (int mi = 0; mi < 4; ++mi) {
      const unsigned int mg = m0 + wm + mi * 16 + fq * 4;
      f32x4 v = acc[mi][ni];
#pragma unroll
      for (int r = 0; r < 4; ++r)
        C[(size_t)(mg + r) * N_DIM + ng] = v[r] * scale + bbv;
    }
  }
}

extern "C" void kernel_launch(void* const* d_in, const int* in_sizes, int n_in,
                              void* d_out, int out_size, void* d_ws, size_t ws_size,
                              hipStream_t stream) {
  const float* x     = (const float*)d_in[0];
  const int*   wq    = (const int*)d_in[1];    // integer inputs arrive as int32
  const float* scale = (const float*)d_in[2];
  const float* bias  = (const float*)d_in[3];
  float* out         = (float*)d_out;

  const size_t xq_bytes = (size_t)M_DIM * K_DIM;       // 33.5 MB
  const size_t wq_bytes = (size_t)N_DIM * K_DIM;       // 45.1 MB
  const size_t rs_bytes = (size_t)M_DIM * sizeof(float);
  const size_t need = xq_bytes + wq_bytes + rs_bytes;

  if (ws_size >= need) {
    signed char* xqp = (signed char*)d_ws;
    signed char* wqp = xqp + xq_bytes;
    float* row_step  = (float*)(wqp + wq_bytes);

    dim3 grid(N_DIM / BN, M_DIM / BM);  // 43 x 32
    quant_x<<<M_DIM, 256, 0, stream>>>(x, xqp, row_step);
    quant_w<<<(unsigned)(wq_bytes / (16 * 256)), 256, 0, stream>>>(
        (const int4*)wq, (int*)wqp);
    gemm_i8<<<grid, 512, 0, stream>>>(xqp, wqp, row_step, bias, scale, out);
  } else {
    dim3 fgrid(N_DIM / FBN, M_DIM / FBM);  // 86 x 64
    gemm_fused<<<fgrid, 256, 0, stream>>>(x, wq, bias, scale, out);
  }
}